// Round 6
// baseline (2150.976 us; speedup 1.0000x reference)
//
#include <hip/hip_runtime.h>

typedef unsigned short u16;
typedef unsigned int   u32;
typedef unsigned long long u64;
typedef signed char    i8;
typedef __attribute__((ext_vector_type(4))) int  i32x4;
typedef __attribute__((ext_vector_type(2))) long i64x2;

// ---------------- problem constants ----------------
#define NSTEP 512
#define NSLOT 4        // ring depth (agent spread provably <= 2)

// ---------------- workspace layout (bytes) ----------------
#define OFF_QX8   0ull
#define SZ_QX8    (32768ull*512)            // x quantized, int8
#define OFF_QWT8  (OFF_QX8 + SZ_QX8)
#define SZ_QT8    (1536ull*512)             // W^T / R^T quantized, int8
#define OFF_QRT8  (OFF_QWT8 + SZ_QT8)
#define OFF_QWX2  (OFF_QRT8 + SZ_QT8)
#define SZ_QWX2   (512ull*4*512*4*3*4)      // Wx gate-packed dwords, 50.3MB
#define OFF_QBX   (OFF_QWX2 + SZ_QWX2)      // 1536 int
#define OFF_QBR   (OFF_QBX + 6144)          // 1536 int
#define OFF_LUT   (OFF_QBR + 6144)          // 256 int sigmoid + 256 int tanh
#define OFF_RING  (OFF_LUT + 2048)          // 4 slots x 4 bg x 4096 u32 tagged words
#define RING_WORDS (NSLOT*4*4096)
#define SZ_RING   (RING_WORDS*4ull)
#define WS_NEED   (OFF_RING + SZ_RING)

// ---------------- helpers ----------------
__device__ __forceinline__ int iclip8(int v){ return v < -128 ? -128 : (v > 127 ? 127 : v); }

// round-half-even of (v / 2^k) for integer v (matches jnp.round on exact values)
__device__ __forceinline__ int rhe(int v, int k){
  int b = v >> k;
  int r = v & ((1 << k) - 1);
  int half = 1 << (k - 1);
  return b + ((r > half) || (r == half && (b & 1)));
}

__device__ __forceinline__ int qi8(float x, float s){
  float q = rintf(x * s);
  q = fminf(fmaxf(q, -128.f), 127.f);
  return (int)q;
}

// MFMA i8 wrapper: tolerate either i32x4- or i64x2-typed builtin signature.
template<typename V>
__device__ __forceinline__ auto mfma_i8_try(V a, V b, i32x4 c, int)
  -> decltype(__builtin_amdgcn_mfma_i32_16x16x64_i8(a, b, c, 0, 0, 0)) {
  return __builtin_amdgcn_mfma_i32_16x16x64_i8(a, b, c, 0, 0, 0);
}
template<typename V>
__device__ __forceinline__ i32x4 mfma_i8_try(V a, V b, i32x4 c, long) {
  return __builtin_amdgcn_mfma_i32_16x16x64_i8(
      __builtin_bit_cast(i64x2, a), __builtin_bit_cast(i64x2, b), c, 0, 0, 0);
}
__device__ __forceinline__ i32x4 mfma_i8(i32x4 a, i32x4 b, i32x4 c){
  return mfma_i8_try(a, b, c, 0);
}

// LLC-coherent (bypass L1+L2) store/zero — the PROVEN exchange fabric
__device__ __forceinline__ void st_llc(u32* p, u32 v){
  asm volatile("global_store_dword %0, %1, off sc0 sc1" :: "v"((u64)p), "v"(v) : "memory");
}
__device__ __forceinline__ void llc_zero16(u32* p){
  i32x4 z = {0,0,0,0};
  asm volatile("global_store_dwordx4 %0, %1, off sc0 sc1" :: "v"((u64)p), "v"(z) : "memory");
}

// ---------------- phase 0: quantization / tables ----------------
__global__ void k0a_qx(const float* __restrict__ x, u32* __restrict__ qx8, int n4){
  int i = blockIdx.x * blockDim.x + threadIdx.x;
  int st = gridDim.x * blockDim.x;
  for (; i < n4; i += st) {
    float4 v = ((const float4*)x)[i];
    u32 b0 = (u32)(qi8(v.x, 16.f) & 0xFF);
    u32 b1 = (u32)(qi8(v.y, 16.f) & 0xFF);
    u32 b2 = (u32)(qi8(v.z, 16.f) & 0xFF);
    u32 b3 = (u32)(qi8(v.w, 16.f) & 0xFF);
    qx8[i] = b0 | (b1 << 8) | (b2 << 16) | (b3 << 24);
  }
}

__global__ void k0b_qwr(const float* __restrict__ W, const float* __restrict__ Rm,
                        i8* __restrict__ qwT8, i8* __restrict__ qrT8){
  int idx = blockIdx.x * 256 + threadIdx.x;       // 0 .. 2*786432-1
  if (idx >= 2*786432) return;
  int m = idx >= 786432;
  int rem = idx - m * 786432;                     // = k*1536 + n (coalesced read)
  int k = rem / 1536;
  int n = rem - k * 1536;
  const float* s = m ? Rm : W;
  i8* d = m ? qrT8 : qwT8;
  d[n*512 + k] = (i8)qi8(s[rem], 1024.f);
}

__global__ void k0c_misc(const float* __restrict__ bx, const float* __restrict__ br,
                         int* __restrict__ qbx, int* __restrict__ qbr,
                         int* __restrict__ lut, u32* __restrict__ ring){
  int i = blockIdx.x * 256 + threadIdx.x;         // 4096 threads
  if (i < 1536) {
    qbx[i] = iclip8((int)rintf(bx[i] * 256.f));
    qbr[i] = iclip8((int)rintf(br[i] * 256.f));
  }
  if (i < 256) {
    double v = (i - 128) * 0.125;                 // all possible pre-activations
    float sg = (float)(1.0 / (1.0 + exp(-v)));
    int qs = (int)rintf(sg * 256.f);
    lut[i] = qs < 0 ? 0 : (qs > 255 ? 255 : qs);
    float th = (float)tanh(v);
    lut[256 + i] = iclip8((int)rintf(th * 128.f));
  }
  // zero the ring EVERY launch via LLC stores: tags >=1, so no leftover matches
  llc_zero16(ring + i*16);
  llc_zero16(ring + i*16 + 4);
  llc_zero16(ring + i*16 + 8);
  llc_zero16(ring + i*16 + 12);
}

// ---------------- phase 1: Wx = fq(xq @ Wq, 4), gate-packed dwords ----------
// 128x128 tile, BK=64, int8 MFMA. Epilogue packs 4 rows (one C/D column of a
// 16-tile) into one dword at qwx2[(((t4*4+bg)*512+hcol)*4+g)*3+gate].
__global__ __launch_bounds__(256) void k1_gemm_wx(const i8* __restrict__ qx8,
                                                  const i8* __restrict__ qwT8,
                                                  u32* __restrict__ qwx2){
  __shared__ i8 xs[128][80];
  __shared__ i8 ws[128][80];
  int bid = blockIdx.x;
  int n0 = (bid % 12) * 128;
  int m0 = (bid / 12) * 128;
  int tid = threadIdx.x;
  int lane = tid & 63, wid = tid >> 6;
  int wm = wid >> 1, wn = wid & 1;
  int g = lane >> 4, l15 = lane & 15;

  i32x4 acc[4][4] = {};
  for (int kc = 0; kc < 512; kc += 64) {
    __syncthreads();
#pragma unroll
    for (int p = 0; p < 4; p++) {
      int idx = p*256 + tid;
      int mat = idx >> 9;
      int i2  = idx & 511;
      int r   = i2 >> 2;
      int c16 = (i2 & 3) << 4;
      const i8* src = mat ? qwT8 : qx8;
      int base = mat ? n0 : m0;
      uint4 val = *(const uint4*)&src[(size_t)(base + r)*512 + kc + c16];
      if (mat) *(uint4*)&ws[r][c16] = val;
      else     *(uint4*)&xs[r][c16] = val;
    }
    __syncthreads();
    i32x4 a[4], b[4];
#pragma unroll
    for (int t = 0; t < 4; t++) {
      a[t] = *(const i32x4*)&xs[wm*64 + t*16 + l15][g*16];
      b[t] = *(const i32x4*)&ws[wn*64 + t*16 + l15][g*16];
    }
#pragma unroll
    for (int i = 0; i < 4; i++)
#pragma unroll
      for (int j = 0; j < 4; j++)
        acc[i][j] = mfma_i8(a[i], b[j], acc[i][j]);
  }
  const int t4idx = (bid / 12) * 2 + wm;          // 64-row block index = timestep pair base
#pragma unroll
  for (int i = 0; i < 4; i++)
#pragma unroll
    for (int j = 0; j < 4; j++) {
      u32 d = 0;
#pragma unroll
      for (int r = 0; r < 4; r++)
        d |= (u32)(iclip8(rhe(acc[i][j][r], 10)) & 0xFF) << (8*r);
      int col1536 = n0 + wn*64 + j*16 + l15;
      int gate = col1536 >> 9;
      int hcol = col1536 & 511;
      qwx2[((((size_t)t4idx*4 + i)*512 + hcol)*4 + g)*3 + gate] = d;
    }
}

// ---------------- phase 2: 512-step recurrence, barrier-free wave-agents ----
// 128 WGs x 64 threads: agent (bg = bid&3, cw = bid>>2) owns 16 h-cols
// end-to-end: z/r/n Rh-tiles (full K=512, registers), gates, h-state, publish.
// NO barriers in the loop; depth-4 tagged LLC ring absorbs agent spread (<=2).
__global__ __launch_bounds__(64, 1) void k2_gru(const float* __restrict__ h0,
                                                const u32* __restrict__ qwx2,
                                                const i8*  __restrict__ qrT8,
                                                const int* __restrict__ qbx,
                                                const int* __restrict__ qbr,
                                                const int* __restrict__ lut,
                                                u32* __restrict__ ring,
                                                float* __restrict__ out){
  const int bid = blockIdx.x;
  const int bg  = bid & 3;
  const int cw  = bid >> 2;                       // 0..31
  const int lane = threadIdx.x;                   // 0..63
  const int g = lane >> 4, l15 = lane & 15;

  __shared__ int l_sig[256], l_th[256];
  for (int e = lane; e < 256; e += 64) { l_sig[e] = lut[e]; l_th[e] = lut[256 + e]; }
  __syncthreads();                                // once, outside the loop

  const int col = cw*16 + l15;                    // lane's h-column

  // ---- R fragments (B operand): 3 gate-tiles x 8 k-chunks, 96 VGPRs
  i32x4 rf[3][8];
#pragma unroll
  for (int n = 0; n < 3; n++) {
    const i8* rp = qrT8 + (size_t)(n*512 + col)*512 + g*16;
#pragma unroll
    for (int m = 0; m < 8; m++)
      rf[n][m] = *(const i32x4*)(rp + m*64);
  }

  const int bxz = qbx[col], bxr = qbx[512 + col], bxn = qbx[1024 + col];
  const int brz = qbr[col], brr = qbr[512 + col], brn = qbr[1024 + col];

  // ---- h state: rows g*4+r (C/D layout rows), this lane's col
  int qh[4];
#pragma unroll
  for (int r = 0; r < 4; r++)
    qh[r] = qi8(h0[(size_t)(bg*16 + g*4 + r)*512 + col], 128.f);

  const u64 ringb = (u64)ring;
  // publish geometry (constant per lane): word packs cols (kp,kp+1) of one row
  const int even = ((lane & 1) == 0);
  const int kp = col & ~1;
  const int rA = g*4 + (even ? 0 : 2);
  const int pw = ((((kp >> 7)*4 + ((kp >> 4) & 3))*16 + rA)*16)
               + (((kp >> 6) & 1) << 3) + ((kp >> 1) & 7);
  const int sh = even ? 0 : 16;

  // ---- publish h(0): slot 0, tag 1
  {
    u32 my = (u32)(qh[0] & 0xFF) | ((u32)(qh[1] & 0xFF) << 8)
           | ((u32)(qh[2] & 0xFF) << 16) | ((u32)qh[3] << 24);
    u32 nb = (u32)__shfl_xor((int)my, 1, 64);
    u32 lo = even ? my : nb, hi = even ? nb : my;
    u32 wA = ((lo >> sh) & 0xFF) | (((hi >> sh) & 0xFF) << 8) | (1u << 16);
    u32 wB = ((lo >> (sh + 8)) & 0xFF) | (((hi >> (sh + 8)) & 0xFF) << 8) | (1u << 16);
    u64 a = ringb + (u64)(bg*16384 + pw*4);
    st_llc((u32*)a, wA);
    st_llc((u32*)(a + 64), wB);
  }

  // ---- Wx preload (t = 0)
  u32 wzd, wrd, wgd;
  {
    const u32* p = qwx2 + (((size_t)bg*512 + col)*4 + g)*3;
    wzd = p[0]; wrd = p[1]; wgd = p[2];
  }

  const u64 laneoff = (u64)((g*16 + l15) * 64);   // A-frag region for batch-row l15

  for (int t = 0; t < NSTEP; t++) {
    const u32 want2 = (u32)(t + 1) | ((u32)(t + 1) << 16);
    const u64 so = ringb + (u64)(((t & 3)*4 + bg) * 16384) + laneoff;
    const u64 a0 = so, a1 = so + 4096, a2 = so + 8192, a3 = so + 12288;
    uint4 p0,p1,p2,p3,p4,p5,p6,p7,p8,p9,p10,p11,p12,p13,p14,p15;
    int rounds = 0;
    for (;;) {
      asm volatile(
        "global_load_dwordx4 %0,  %16, off sc0 sc1\n\t"
        "global_load_dwordx4 %1,  %16, off offset:16 sc0 sc1\n\t"
        "global_load_dwordx4 %2,  %16, off offset:32 sc0 sc1\n\t"
        "global_load_dwordx4 %3,  %16, off offset:48 sc0 sc1\n\t"
        "global_load_dwordx4 %4,  %17, off sc0 sc1\n\t"
        "global_load_dwordx4 %5,  %17, off offset:16 sc0 sc1\n\t"
        "global_load_dwordx4 %6,  %17, off offset:32 sc0 sc1\n\t"
        "global_load_dwordx4 %7,  %17, off offset:48 sc0 sc1\n\t"
        "global_load_dwordx4 %8,  %18, off sc0 sc1\n\t"
        "global_load_dwordx4 %9,  %18, off offset:16 sc0 sc1\n\t"
        "global_load_dwordx4 %10, %18, off offset:32 sc0 sc1\n\t"
        "global_load_dwordx4 %11, %18, off offset:48 sc0 sc1\n\t"
        "global_load_dwordx4 %12, %19, off sc0 sc1\n\t"
        "global_load_dwordx4 %13, %19, off offset:16 sc0 sc1\n\t"
        "global_load_dwordx4 %14, %19, off offset:32 sc0 sc1\n\t"
        "global_load_dwordx4 %15, %19, off offset:48 sc0 sc1\n\t"
        "s_waitcnt vmcnt(0)"
        : "=&v"(p0), "=&v"(p1), "=&v"(p2), "=&v"(p3),
          "=&v"(p4), "=&v"(p5), "=&v"(p6), "=&v"(p7),
          "=&v"(p8), "=&v"(p9), "=&v"(p10), "=&v"(p11),
          "=&v"(p12), "=&v"(p13), "=&v"(p14), "=&v"(p15)
        : "v"(a0), "v"(a1), "v"(a2), "v"(a3)
        : "memory");
      u32 diff = 0u;
#define TCHK(P) \
      diff |= __builtin_amdgcn_perm((P).y, (P).x, 0x07060302u) ^ want2; \
      diff |= __builtin_amdgcn_perm((P).w, (P).z, 0x07060302u) ^ want2;
      TCHK(p0) TCHK(p1) TCHK(p2) TCHK(p3) TCHK(p4) TCHK(p5) TCHK(p6) TCHK(p7)
      TCHK(p8) TCHK(p9) TCHK(p10) TCHK(p11) TCHK(p12) TCHK(p13) TCHK(p14) TCHK(p15)
#undef TCHK
      if (diff == 0u) break;
      if (++rounds > (1 << 22)) break;            // hang-prevention only
      if (rounds >= 2) __builtin_amdgcn_s_sleep(1);
    }

    // next-step Wx prefetch (hides under MFMAs; drained by next poll)
    u32 nz = 0, nr = 0, ng = 0;
    if (t < NSTEP - 1) {
      const u32* p = qwx2 + ((((size_t)(t + 1)*4 + bg)*512 + col)*4 + g)*3;
      nz = p[0]; nr = p[1]; ng = p[2];
    }

    // ---- pack A (strip tags) and run 24 MFMAs: acc[n] over full K=512
    i32x4 acc0 = {}, acc1 = {}, acc2 = {};
#define PACKA(A, Pa, Pb) \
      A.x = (int)__builtin_amdgcn_perm((Pa).y, (Pa).x, 0x05040100u); \
      A.y = (int)__builtin_amdgcn_perm((Pa).w, (Pa).z, 0x05040100u); \
      A.z = (int)__builtin_amdgcn_perm((Pb).y, (Pb).x, 0x05040100u); \
      A.w = (int)__builtin_amdgcn_perm((Pb).w, (Pb).z, 0x05040100u);
#define DO_W(w, Pa, Pb, Pc, Pd) { \
      i32x4 A0, A1; \
      PACKA(A0, Pa, Pb) PACKA(A1, Pc, Pd) \
      acc0 = mfma_i8(A0, rf[0][2*(w)],     acc0); \
      acc1 = mfma_i8(A0, rf[1][2*(w)],     acc1); \
      acc2 = mfma_i8(A0, rf[2][2*(w)],     acc2); \
      acc0 = mfma_i8(A1, rf[0][2*(w) + 1], acc0); \
      acc1 = mfma_i8(A1, rf[1][2*(w) + 1], acc1); \
      acc2 = mfma_i8(A1, rf[2][2*(w) + 1], acc2); }
    DO_W(0, p0, p1, p2, p3)
    DO_W(1, p4, p5, p6, p7)
    DO_W(2, p8, p9, p10, p11)
    DO_W(3, p12, p13, p14, p15)
#undef DO_W
#undef PACKA

    // ---- gates, fully in-lane (z/r/n for (row,col) share the lane)
#pragma unroll
    for (int r = 0; r < 4; r++) {
      int rz = iclip8(rhe(iclip8(rhe(acc0[r], 13))*16 + brz, 4));
      int rr = iclip8(rhe(iclip8(rhe(acc1[r], 13))*16 + brr, 4));
      int rg = iclip8(rhe(iclip8(rhe(acc2[r], 13))*16 + brn, 4));
      int wz = (int)(i8)((wzd >> (8*r)) & 0xFF);
      int wr = (int)(i8)((wrd >> (8*r)) & 0xFF);
      int wg = (int)(i8)((wgd >> (8*r)) & 0xFF);
      int uz  = l_sig[128 + iclip8(rhe(16*(wz + rz) + bxz, 5))];
      int ur  = l_sig[128 + iclip8(rhe(16*(wr + rr) + bxr, 5))];
      int qrh = iclip8(rhe(ur * rg, 8));
      int qg  = l_th[128 + iclip8(rhe(16*(wg + qrh) + bxn, 5))];
      int qold = iclip8(rhe(uz * qh[r], 8));
      int qnew = iclip8(rhe((256 - uz) * qg, 8));
      qh[r] = iclip8(qold + qnew);
    }

    // ---- publish h(t+1) FIRST: slot (t+1)&3, tag t+2
    {
      u32 my = (u32)(qh[0] & 0xFF) | ((u32)(qh[1] & 0xFF) << 8)
             | ((u32)(qh[2] & 0xFF) << 16) | ((u32)qh[3] << 24);
      u32 nb = (u32)__shfl_xor((int)my, 1, 64);
      u32 lo = even ? my : nb, hi = even ? nb : my;
      u32 tg = (u32)(t + 2) << 16;
      u32 wA = ((lo >> sh) & 0xFF) | (((hi >> sh) & 0xFF) << 8) | tg;
      u32 wB = ((lo >> (sh + 8)) & 0xFF) | (((hi >> (sh + 8)) & 0xFF) << 8) | tg;
      u64 a = ringb + (u64)((((t + 1) & 3)*4 + bg)*16384 + pw*4);
      st_llc((u32*)a, wA);
      st_llc((u32*)(a + 64), wB);
    }

    // ---- out stores (16-lane 64B coalesced segments per row)
#pragma unroll
    for (int r = 0; r < 4; r++)
      out[((size_t)t*64 + bg*16 + g*4 + r)*512 + col] = qh[r] * 0.0078125f;

    wzd = nz; wrd = nr; wgd = ng;
  }
}

// ---------------- launch ----------------
extern "C" void kernel_launch(void* const* d_in, const int* in_sizes, int n_in,
                              void* d_out, int out_size, void* d_ws, size_t ws_size,
                              hipStream_t stream) {
  const float* x  = (const float*)d_in[0];
  const float* h0 = (const float*)d_in[1];
  const float* W  = (const float*)d_in[2];
  const float* R  = (const float*)d_in[3];
  const float* bx = (const float*)d_in[4];
  const float* br = (const float*)d_in[5];
  float* out = (float*)d_out;

  if (ws_size < WS_NEED) return;   // insufficient scratch; fail loudly

  char* ws = (char*)d_ws;
  i8*  qx8   = (i8*) (ws + OFF_QX8);
  i8*  qwT8  = (i8*) (ws + OFF_QWT8);
  i8*  qrT8  = (i8*) (ws + OFF_QRT8);
  u32* qwx2  = (u32*)(ws + OFF_QWX2);
  int* qbx   = (int*)(ws + OFF_QBX);
  int* qbr   = (int*)(ws + OFF_QBR);
  int* lut   = (int*)(ws + OFF_LUT);
  u32* ring  = (u32*)(ws + OFF_RING);

  k0a_qx  <<<2048, 256, 0, stream>>>(x, (u32*)qx8, 32768*512/4);
  k0b_qwr <<<6144, 256, 0, stream>>>(W, R, qwT8, qrT8);
  k0c_misc<<<16,   256, 0, stream>>>(bx, br, qbx, qbr, lut, ring);
  k1_gemm_wx<<<3072, 256, 0, stream>>>(qx8, qwT8, qwx2);
  k2_gru  <<<128, 64, 0, stream>>>(h0, qwx2, qrT8, qbx, qbr, lut, ring, out);
}